// Round 6
// baseline (1681.735 us; speedup 1.0000x reference)
//
#include <hip/hip_runtime.h>

typedef _Float16 f16;
typedef _Float16 f16x4 __attribute__((ext_vector_type(4)));
typedef _Float16 f16x8 __attribute__((ext_vector_type(8)));
typedef float f32x4 __attribute__((ext_vector_type(4)));

#define TLEN 2048
#define TPAD 2050     // gates3 time extent (2 pad steps: prefetch needs no clamp)
#define NCOL 640      // padded columns: 160 units x 4 gates, col = u*4 + G
#define K1   1.4426950408889634f   // log2(e)
#define K2   2.8853900817779268f   // 2*log2(e)

__device__ __forceinline__ f16x8 as_f16x8(f32x4 v) {
    union { f32x4 f; f16x8 h; } u; u.f = v; return u.h;
}

// ---------------------------------------------------------------------------
// Prep: MFMA B-fragment-ordered fp16 w_ih / w_hh, columns ordered
// col = unit*4 + gate (so one 16-wide n-tile covers 4 units x 4 gates and
// 8 waves x 5 tiles splits evenly), PRE-SCALED per gate (i,f,o: -K1; g: +K2)
// so the scan's exp2 args need no multiply.  Fragment layout:
// [nt(40)][kt(5)][lane(64)][e(8)], col = nt*16 + (lane&15),
// k = kt*32 + (lane>>4)*8 + e.  biasp[col] gets the same scale.
// ---------------------------------------------------------------------------
__global__ void prep_weights(const float* __restrict__ w_ih,
                             const float* __restrict__ w_hh,
                             const float* __restrict__ b_ih,
                             const float* __restrict__ b_hh,
                             f16* __restrict__ wihf, f16* __restrict__ whhf,
                             float* __restrict__ biasp)
{
    const int idx = blockIdx.x * blockDim.x + threadIdx.x;
    const int stride = gridDim.x * blockDim.x;
    for (int i = idx; i < 40 * 5 * 64 * 8; i += stride) {
        const int e = i & 7;
        const int lane = (i >> 3) & 63;
        const int kt = (i >> 9) % 5;
        const int nt = i / 2560;
        const int colg = nt * 16 + (lane & 15);
        const int u = colg >> 2, G = colg & 3;
        const int k = kt * 32 + (lane >> 4) * 8 + e;
        const float sc = (G == 2) ? K2 : -K1;
        f16 vi = (f16)0.f, vh = (f16)0.f;
        if (u < 150) {
            const int row = G * 150 + u;
            if (k < 144) vi = (f16)(w_ih[row * 144 + k] * sc);
            if (k < 150) vh = (f16)(w_hh[row * 150 + k] * sc);
        }
        wihf[i] = vi;
        whhf[i] = vh;
    }
    for (int i = idx; i < NCOL; i += stride) {
        const int u = i >> 2, G = i & 3;
        const float sc = (G == 2) ? K2 : -K1;
        biasp[i] = (u < 150) ? (b_ih[G * 150 + u] + b_hh[G * 150 + u]) * sc : 0.f;
    }
}

// ---------------------------------------------------------------------------
// Conv 3x3 VALID (17->4) + bias + ReLU.  4 (b,t) tiles per 256-thread block.
// Writes y in [t*16+b][160] fp16 (K padded 144->160 with zeros).
// ---------------------------------------------------------------------------
__global__ __launch_bounds__(256) void conv_relu(
    const float* __restrict__ in, const float* __restrict__ cw,
    const float* __restrict__ cb, f16* __restrict__ y)
{
    __shared__ float s_in[4][1088];
    __shared__ float s_w[612];
    __shared__ float s_b[4];
    const int tid = threadIdx.x, sub = tid >> 6, lt = tid & 63;
    const int bt = blockIdx.x * 4 + sub;
    const float* ip = in + (size_t)bt * 1088;
    #pragma unroll
    for (int i = 0; i < 17; ++i) s_in[sub][lt + i * 64] = ip[lt + i * 64];
    for (int i = tid; i < 612; i += 256) s_w[i] = cw[i];
    if (tid < 4) s_b[tid] = cb[tid];
    __syncthreads();
    const int b = bt >> 11, t = bt & 2047;
    f16* yr = y + (size_t)(t * 16 + b) * 160;
    for (int i = lt; i < 160; i += 64) {
        float v = 0.f;
        if (i < 144) {
            const int oc = i / 36, rr = i % 36, oy = rr / 6, ox = rr % 6;
            float acc = s_b[oc];
            const float* wp = s_w + oc * 153;
            const float* bp = &s_in[sub][oy * 8 + ox];
            #pragma unroll
            for (int ic = 0; ic < 17; ++ic)
                #pragma unroll
                for (int ky = 0; ky < 3; ++ky)
                    #pragma unroll
                    for (int kx = 0; kx < 3; ++kx)
                        acc += bp[ic * 64 + ky * 8 + kx] * wp[ic * 9 + ky * 3 + kx];
            v = fmaxf(acc, 0.f);
        }
        yr[i] = (f16)v;
    }
}

// ---------------------------------------------------------------------------
// gates_x = y @ w_ih_scaled^T + bias_scaled.  One block (10 waves x 4 tiles)
// per timestep.  Output layout [b][t(TPAD)][col(640)] flat f16, cols in the
// interleaved u*4+G order the scan consumes.
// ---------------------------------------------------------------------------
__global__ __launch_bounds__(640, 1) void gates_gemm(
    const f16* __restrict__ y, const f16* __restrict__ wihf,
    const float* __restrict__ biasp, f16* __restrict__ gates3)
{
    const int tid = threadIdx.x, wv = tid >> 6, lane = tid & 63;
    const int col = lane & 15, grp = lane >> 4;
    const int t = blockIdx.x;
    f16x8 a[5];
    const f16* yr = y + (size_t)(t * 16 + col) * 160;
    #pragma unroll
    for (int kt = 0; kt < 5; ++kt)
        a[kt] = *(const f16x8*)(yr + kt * 32 + grp * 8);
    #pragma unroll
    for (int i = 0; i < 4; ++i) {
        const int nt = wv * 4 + i;
        f32x4 acc = {0.f, 0.f, 0.f, 0.f};
        const f16* wf = wihf + (size_t)(nt * 5) * 512;
        #pragma unroll
        for (int kt = 0; kt < 5; ++kt) {
            f16x8 bf = *(const f16x8*)(wf + kt * 512 + lane * 8);
            acc = __builtin_amdgcn_mfma_f32_16x16x32_f16(a[kt], bf, acc, 0, 0, 0);
        }
        const int colg = nt * 16 + col;
        const float bb = biasp[colg];
        #pragma unroll
        for (int r = 0; r < 4; ++r)
            gates3[((size_t)(grp * 4 + r) * TPAD + t) * NCOL + colg] = (f16)(acc[r] + bb);
    }
}

// ---------------------------------------------------------------------------
// Batch-parallel persistent LSTM scan: 16 WGs (one batch row), 512 threads =
// 8 waves = 2 waves/SIMD -> per-SIMD MFMA load balanced at 50/step (the
// 10-wave version's 3/3/2/2 split made the worst SIMD do 60).  Wave w owns
// n-tiles 5w..5w+4 = columns 80w..80w+79 = units 20w..20w+19 x 4 gates.
// Gate gather for activation is a same-wave LDS round-trip (no barrier):
// lanes 0-15 write acc[i][0] (row 0) into a stride-5-padded region; lanes
// 0-19 read their unit's 4 gates back, compute act, write h into the
// A-fragment-ordered hN double buffer.  ONE barrier per step.
// ---------------------------------------------------------------------------
__device__ __forceinline__ void lstm_step8(
    int t, f16 (&pf)[5], const f16* __restrict__ gb,
    const f32x4 (&bfrag)[5][5], f16* hNs, float* gbuf,
    float& cst, int lane, int w, int gwr, int wel)
{
    const int cur = t & 1;
    const bool r0 = (lane < 16);

    // C-init: row 0 gets gates_x (pre-scaled), rows 1-15 zero.
    f32x4 acc[5];
    #pragma unroll
    for (int i = 0; i < 5; ++i)
        acc[i] = (f32x4){r0 ? (float)pf[i] : 0.f, 0.f, 0.f, 0.f};

    // Refill prefetch slot for step t+2 (gates3 is TPAD-padded; loads stay
    // in flight across the raw barrier: vmcnt never drained).
    #pragma unroll
    for (int i = 0; i < 5; ++i)
        pf[i] = gb[(size_t)(t + 2) * NCOL + 16 * i];

    // h @ w_hh^T (scaled): 5 linear ds_read_b128 + 25 MFMA (5 tiles x 5 kt).
    const f16* hr = hNs + cur * 2560 + lane * 8;
    #pragma unroll
    for (int kt = 0; kt < 5; ++kt) {
        const f16x8 a = *(const f16x8*)(hr + kt * 512);
        #pragma unroll
        for (int i = 0; i < 5; ++i)
            acc[i] = __builtin_amdgcn_mfma_f32_16x16x32_f16(
                a, as_f16x8(bfrag[i][kt]), acc[i], 0, 0, 0);
    }

    // Gate extraction: lanes 0-15 hold row 0 of each tile; unit-local
    // u' = i*4 + (lane>>2), gate G = lane&3 -> dword w*100 + u'*5 + G
    // (stride 5 => conflict-free; distinct dwords per lane).
    if (lane < 16) {
        #pragma unroll
        for (int i = 0; i < 5; ++i)
            gbuf[gwr + i * 20] = acc[i][0];
    }
    // Same-wave write->read through LDS: drain to be safe (cheap).
    asm volatile("s_waitcnt lgkmcnt(0)" ::: "memory");

    // Activation: lane l<20 owns unit u = w*20 + l; reads 4 gates at
    // stride-5 dwords (banks 5l%32: conflict-free).  Pre-scaled args.
    if (lane < 20) {
        const float* gp = gbuf + w * 100 + lane * 5;
        const float ai = fminf(gp[0], 38.f);
        const float af = fminf(gp[1], 38.f);
        const float ag = fminf(gp[2], 38.f);
        const float ao = fminf(gp[3], 38.f);
        const float ei = __builtin_amdgcn_exp2f(ai);   // e^{-i}
        const float ef = __builtin_amdgcn_exp2f(af);   // e^{-f}
        const float eg = __builtin_amdgcn_exp2f(ag);   // e^{2g}
        const float eo = __builtin_amdgcn_exp2f(ao);   // e^{-o}
        const float ip1 = 1.f + ei, fp1 = 1.f + ef;
        const float gp1 = eg + 1.f, gm1 = eg - 1.f, op1 = 1.f + eo;
        const float dig = ip1 * gp1;
        const float num = cst * dig + gm1 * fp1;
        const float c = num * __builtin_amdgcn_rcpf(fp1 * dig);
        cst = c;
        const float ec = __builtin_amdgcn_exp2f(fminf(K2 * c, 80.f));
        const float h = (ec - 1.f) * __builtin_amdgcn_rcpf(op1 * (ec + 1.f));
        hNs[(cur ^ 1) * 2560 + wel] = (f16)h;
    }

    // Drain LDS ops; ONE raw barrier per step (global prefetches in flight).
    asm volatile("s_waitcnt lgkmcnt(0)" ::: "memory");
    __builtin_amdgcn_s_barrier();
    __builtin_amdgcn_sched_barrier(0);
}

__global__ __launch_bounds__(512, 1) void lstm_scan(
    const f16* __restrict__ gates3, const f16* __restrict__ whhf,
    const float* __restrict__ last_w, const float* __restrict__ last_b,
    float* __restrict__ out)
{
    __shared__ __align__(16) f16 hN[2 * 2560];   // [buf][kt(5)][lane(64)][e(8)]
    __shared__ float gbuf[800];                  // 8 waves x 20 units x 5 dwords
    const int b = blockIdx.x;
    const int tid = threadIdx.x, w = tid >> 6, lane = tid & 63;
    // gate-extract write base (lanes 0-15): dword w*100 + (lane>>2)*5 + (lane&3)
    const int gwr = w * 100 + (lane >> 2) * 5 + (lane & 3);
    // h write element for unit u = w*20 + lane (lanes 0-19):
    const int u = w * 20 + lane;
    const int wel = (u >> 5) * 512 + ((u >> 3) & 3) * 128 + (u & 7);

    for (int i = tid; i < 2 * 2560; i += 512) hN[i] = (f16)0.f;

    // w_hh B-fragments for this wave's 5 tiles (live in VGPR/AGPR file;
    // 2 waves/SIMD -> 256-reg budget, no pressure).
    f32x4 bfrag[5][5];
    #pragma unroll
    for (int i = 0; i < 5; ++i)
        #pragma unroll
        for (int kt = 0; kt < 5; ++kt)
            bfrag[i][kt] =
                *(const f32x4*)(whhf + (size_t)((((5 * w + i) * 5) + kt) * 64 + lane) * 8);

    float cst = 0.f;
    __syncthreads();

    // Per-lane gates base: lane reads cols {80w + 16i + (lane&15)} each step.
    const f16* gb = gates3 + (size_t)b * TPAD * NCOL + 80 * w + (lane & 15);

    f16 pA[5], pB[5];
    #pragma unroll
    for (int i = 0; i < 5; ++i) {
        pA[i] = gb[(size_t)0 * NCOL + 16 * i];
        pB[i] = gb[(size_t)1 * NCOL + 16 * i];
    }

    #pragma unroll 1
    for (int tb = 0; tb < TLEN; tb += 2) {
        lstm_step8(tb,     pA, gb, bfrag, hN, gbuf, cst, lane, w, gwr, wel);
        lstm_step8(tb + 1, pB, gb, bfrag, hN, gbuf, cst, lane, w, gwr, wel);
    }

    // Final projection (step 2047 wrote buf 0): out[b] = h_T @ last_w^T + last_b
    if (tid < 2) {
        float s = last_b[tid];
        for (int j = 0; j < 150; ++j) {
            const int elem = (j >> 5) * 512 + ((j >> 3) & 3) * 128 + (j & 7);
            s += (float)hN[elem] * last_w[tid * 150 + j];
        }
        out[b * 2 + tid] = s;
    }
}

// ---------------------------------------------------------------------------
extern "C" void kernel_launch(void* const* d_in, const int* in_sizes, int n_in,
                              void* d_out, int out_size, void* d_ws, size_t ws_size,
                              hipStream_t stream) {
    const float* inp    = (const float*)d_in[0];
    const float* conv_w = (const float*)d_in[1];
    const float* conv_b = (const float*)d_in[2];
    const float* w_ih   = (const float*)d_in[3];
    const float* w_hh   = (const float*)d_in[4];
    const float* b_ih   = (const float*)d_in[5];
    const float* b_hh   = (const float*)d_in[6];
    const float* last_w = (const float*)d_in[7];
    const float* last_b = (const float*)d_in[8];
    float* out = (float*)d_out;

    char* ws = (char*)d_ws;
    f16*   y      = (f16*)(ws);                        // 32768*160*2   = 10,485,760 B
    f16*   gates3 = (f16*)(ws + 10485760);             // 16*2050*640*2 = 41,984,000 B
    f16*   wihf   = (f16*)(ws + 10485760 + 41984000);          // 204,800 B
    f16*   whhf   = (f16*)(ws + 10485760 + 41984000 + 204800); // 204,800 B
    float* biasp  = (float*)(ws + 10485760 + 41984000 + 409600); // 2,560 B

    prep_weights<<<120, 256, 0, stream>>>(w_ih, w_hh, b_ih, b_hh, wihf, whhf, biasp);
    conv_relu<<<8192, 256, 0, stream>>>(inp, conv_w, conv_b, y);
    gates_gemm<<<2048, 640, 0, stream>>>(y, wihf, biasp, gates3);
    lstm_scan<<<16, 512, 0, stream>>>(gates3, whhf, last_w, last_b, out);
}

// Round 7
// 1483.597 us; speedup vs baseline: 1.1336x; 1.1336x over previous
//
#include <hip/hip_runtime.h>

typedef _Float16 f16;
typedef _Float16 f16x4 __attribute__((ext_vector_type(4)));
typedef _Float16 f16x8 __attribute__((ext_vector_type(8)));
typedef float f32x4 __attribute__((ext_vector_type(4)));

#define TLEN 2048
#define TPAD 2050     // gates3 time extent (2 pad steps: prefetch needs no clamp)
#define NCOL 640      // padded columns: 160 units x 4 gates, col = u*4 + G
#define K1   1.4426950408889634f   // log2(e)
#define K2   2.8853900817779268f   // 2*log2(e)

__device__ __forceinline__ f16x8 as_f16x8(f32x4 v) {
    union { f32x4 f; f16x8 h; } u; u.f = v; return u.h;
}

// ---------------------------------------------------------------------------
// Prep: MFMA fragment-ordered fp16 w_ih / w_hh, columns ordered
// col = unit*4 + gate, PRE-SCALED per gate (i,f,o: -K1; g: +K2) so the
// scan's exp2 args need no multiply.  Fragment layout:
// [nt(40)][kt(5)][lane(64)][e(8)], col = nt*16 + (lane&15),
// k = kt*32 + (lane>>4)*8 + e.  biasp[col] gets the same scale.
// ---------------------------------------------------------------------------
__global__ void prep_weights(const float* __restrict__ w_ih,
                             const float* __restrict__ w_hh,
                             const float* __restrict__ b_ih,
                             const float* __restrict__ b_hh,
                             f16* __restrict__ wihf, f16* __restrict__ whhf,
                             float* __restrict__ biasp)
{
    const int idx = blockIdx.x * blockDim.x + threadIdx.x;
    const int stride = gridDim.x * blockDim.x;
    for (int i = idx; i < 40 * 5 * 64 * 8; i += stride) {
        const int e = i & 7;
        const int lane = (i >> 3) & 63;
        const int kt = (i >> 9) % 5;
        const int nt = i / 2560;
        const int colg = nt * 16 + (lane & 15);
        const int u = colg >> 2, G = colg & 3;
        const int k = kt * 32 + (lane >> 4) * 8 + e;
        const float sc = (G == 2) ? K2 : -K1;
        f16 vi = (f16)0.f, vh = (f16)0.f;
        if (u < 150) {
            const int row = G * 150 + u;
            if (k < 144) vi = (f16)(w_ih[row * 144 + k] * sc);
            if (k < 150) vh = (f16)(w_hh[row * 150 + k] * sc);
        }
        wihf[i] = vi;
        whhf[i] = vh;
    }
    for (int i = idx; i < NCOL; i += stride) {
        const int u = i >> 2, G = i & 3;
        const float sc = (G == 2) ? K2 : -K1;
        biasp[i] = (u < 150) ? (b_ih[G * 150 + u] + b_hh[G * 150 + u]) * sc : 0.f;
    }
}

// ---------------------------------------------------------------------------
// Conv 3x3 VALID (17->4) + bias + ReLU.  4 (b,t) tiles per 256-thread block.
// Writes y in [t*16+b][160] fp16 (K padded 144->160 with zeros).
// ---------------------------------------------------------------------------
__global__ __launch_bounds__(256) void conv_relu(
    const float* __restrict__ in, const float* __restrict__ cw,
    const float* __restrict__ cb, f16* __restrict__ y)
{
    __shared__ float s_in[4][1088];
    __shared__ float s_w[612];
    __shared__ float s_b[4];
    const int tid = threadIdx.x, sub = tid >> 6, lt = tid & 63;
    const int bt = blockIdx.x * 4 + sub;
    const float* ip = in + (size_t)bt * 1088;
    #pragma unroll
    for (int i = 0; i < 17; ++i) s_in[sub][lt + i * 64] = ip[lt + i * 64];
    for (int i = tid; i < 612; i += 256) s_w[i] = cw[i];
    if (tid < 4) s_b[tid] = cb[tid];
    __syncthreads();
    const int b = bt >> 11, t = bt & 2047;
    f16* yr = y + (size_t)(t * 16 + b) * 160;
    for (int i = lt; i < 160; i += 64) {
        float v = 0.f;
        if (i < 144) {
            const int oc = i / 36, rr = i % 36, oy = rr / 6, ox = rr % 6;
            float acc = s_b[oc];
            const float* wp = s_w + oc * 153;
            const float* bp = &s_in[sub][oy * 8 + ox];
            #pragma unroll
            for (int ic = 0; ic < 17; ++ic)
                #pragma unroll
                for (int ky = 0; ky < 3; ++ky)
                    #pragma unroll
                    for (int kx = 0; kx < 3; ++kx)
                        acc += bp[ic * 64 + ky * 8 + kx] * wp[ic * 9 + ky * 3 + kx];
            v = fmaxf(acc, 0.f);
        }
        yr[i] = (f16)v;
    }
}

// ---------------------------------------------------------------------------
// gates_x = y @ w_ih_scaled^T + bias_scaled.  One block (10 waves x 4 tiles)
// per timestep.  Output layout [b][t(TPAD)][col(640)] flat f16, cols in the
// interleaved u*4+G order the scan consumes.
// ---------------------------------------------------------------------------
__global__ __launch_bounds__(640, 1) void gates_gemm(
    const f16* __restrict__ y, const f16* __restrict__ wihf,
    const float* __restrict__ biasp, f16* __restrict__ gates3)
{
    const int tid = threadIdx.x, wv = tid >> 6, lane = tid & 63;
    const int col = lane & 15, grp = lane >> 4;
    const int t = blockIdx.x;
    f16x8 a[5];
    const f16* yr = y + (size_t)(t * 16 + col) * 160;
    #pragma unroll
    for (int kt = 0; kt < 5; ++kt)
        a[kt] = *(const f16x8*)(yr + kt * 32 + grp * 8);
    #pragma unroll
    for (int i = 0; i < 4; ++i) {
        const int nt = wv * 4 + i;
        f32x4 acc = {0.f, 0.f, 0.f, 0.f};
        const f16* wf = wihf + (size_t)(nt * 5) * 512;
        #pragma unroll
        for (int kt = 0; kt < 5; ++kt) {
            f16x8 bf = *(const f16x8*)(wf + kt * 512 + lane * 8);
            acc = __builtin_amdgcn_mfma_f32_16x16x32_f16(a[kt], bf, acc, 0, 0, 0);
        }
        const int colg = nt * 16 + col;
        const float bb = biasp[colg];
        #pragma unroll
        for (int r = 0; r < 4; ++r)
            gates3[((size_t)(grp * 4 + r) * TPAD + t) * NCOL + colg] = (f16)(acc[r] + bb);
    }
}

// ---------------------------------------------------------------------------
// Batch-parallel persistent LSTM scan: 16 WGs (one batch row each), 512
// threads = 8 waves = 2/SIMD (balanced: 50 MFMA/SIMD/step).
// OPERAND SWAP: A = w_hh fragments (M = output cols, resident in regs),
// B = h broadcast (N = batch; h is a LINEAR 160-f16 LDS array, read as
// conflict-free broadcast ds_read_b128).  With col order u*4+G, lane
// (grp = lane>>4) of tile nt holds all 4 gates of unit 4*nt+grp in its 4
// acc regs -> activation is fully in-register, NO gather.  All 16 C-cols
// are identical (h broadcast), so col c computes the act for tile (c mod 5)
// via a cndmask select: ONE act per lane per step (5x fewer trans ops).
// Col c<5 writes h[20w+4c+grp].  One raw barrier per step; gates prefetched
// 2 steps ahead (vmcnt never drained).
// ---------------------------------------------------------------------------
__device__ __forceinline__ void lstm_step9(
    int t, f16x4 (&pf)[5], const f16* __restrict__ gb,
    const f32x4 (&afrag)[5][5], f16* hbufs, float& cst,
    int grp, int sel, bool wr, int wel)
{
    const int cur = t & 1;

    // C-init from prefetched gates_x: acc[i][r] = gate r of unit 4(5w+i)+grp
    // (identical across cols, matching the broadcast-B invariance).
    f32x4 acc[5];
    #pragma unroll
    for (int i = 0; i < 5; ++i) {
        acc[i][0] = (float)pf[i][0];
        acc[i][1] = (float)pf[i][1];
        acc[i][2] = (float)pf[i][2];
        acc[i][3] = (float)pf[i][3];
    }

    // Refill prefetch slot for step t+2 (TPAD-padded; stays in flight).
    #pragma unroll
    for (int i = 0; i < 5; ++i)
        pf[i] = *(const f16x4*)(gb + (size_t)(t + 2) * NCOL + 16 * i);

    // B-fragments: linear broadcast reads of h; 5 kt x 5 tiles = 25 MFMA.
    const f16* hr = hbufs + cur * 160 + grp * 8;
    #pragma unroll
    for (int kt = 0; kt < 5; ++kt) {
        const f16x8 bf = *(const f16x8*)(hr + kt * 32);
        #pragma unroll
        for (int i = 0; i < 5; ++i)
            acc[i] = __builtin_amdgcn_mfma_f32_16x16x32_f16(
                afrag[i][kt], bf, acc[i], 0, 0, 0);
    }

    // Select this lane's tile (sel = col mod 5) -- static unroll, cndmasks.
    float g0 = acc[0][0], g1 = acc[0][1], g2 = acc[0][2], g3 = acc[0][3];
    #pragma unroll
    for (int i = 1; i < 5; ++i) {
        const bool p = (sel == i);
        g0 = p ? acc[i][0] : g0;
        g1 = p ? acc[i][1] : g1;
        g2 = p ? acc[i][2] : g2;
        g3 = p ? acc[i][3] : g3;
    }

    // Activation (pre-scaled args; direct form, independent rcps).
    const float ei = __builtin_amdgcn_exp2f(fminf(g0, 38.f));   // e^{-i}
    const float ef = __builtin_amdgcn_exp2f(fminf(g1, 38.f));   // e^{-f}
    const float eg = __builtin_amdgcn_exp2f(fminf(g2, 38.f));   // e^{2g}
    const float eo = __builtin_amdgcn_exp2f(fminf(g3, 38.f));   // e^{-o}
    const float sig_i = __builtin_amdgcn_rcpf(1.f + ei);
    const float sig_f = __builtin_amdgcn_rcpf(1.f + ef);
    const float sig_o = __builtin_amdgcn_rcpf(1.f + eo);
    const float tng   = (eg - 1.f) * __builtin_amdgcn_rcpf(eg + 1.f);
    const float c = sig_f * cst + sig_i * tng;
    cst = c;
    const float ec = __builtin_amdgcn_exp2f(fminf(K2 * c, 80.f));
    const float tnc = (ec - 1.f) * __builtin_amdgcn_rcpf(ec + 1.f);
    if (wr) hbufs[(cur ^ 1) * 160 + wel] = (f16)(sig_o * tnc);

    // Drain LDS ops; ONE raw barrier per step (global prefetches in flight).
    asm volatile("s_waitcnt lgkmcnt(0)" ::: "memory");
    __builtin_amdgcn_s_barrier();
    __builtin_amdgcn_sched_barrier(0);
}

__global__ __launch_bounds__(512, 1) void lstm_scan(
    const f16* __restrict__ gates3, const f16* __restrict__ whhf,
    const float* __restrict__ last_w, const float* __restrict__ last_b,
    float* __restrict__ out)
{
    __shared__ __align__(16) f16 hbufs[2 * 160];   // linear h, double-buffered
    const int b = blockIdx.x;
    const int tid = threadIdx.x, w = tid >> 6, lane = tid & 63;
    const int col = lane & 15, grp = lane >> 4;
    const int sel = (col < 5) ? col : ((col < 10) ? col - 5 : ((col < 15) ? col - 10 : 0));
    const bool wr = (col < 5);
    const int wel = 20 * w + 4 * sel + grp;        // h index this lane writes

    for (int i = tid; i < 2 * 160; i += 512) hbufs[i] = (f16)0.f;

    // w_hh A-fragments for this wave's 5 tiles (resident in VGPR/AGPR file).
    f32x4 afrag[5][5];
    #pragma unroll
    for (int i = 0; i < 5; ++i)
        #pragma unroll
        for (int kt = 0; kt < 5; ++kt)
            afrag[i][kt] =
                *(const f32x4*)(whhf + (size_t)((((5 * w + i) * 5) + kt) * 64 + lane) * 8);

    float cst = 0.f;
    __syncthreads();

    // Gates base: this lane consumes cols 80w + 16i + 4grp + (0..3).
    const f16* gb = gates3 + (size_t)b * TPAD * NCOL + 80 * w + 4 * grp;

    f16x4 pA[5], pB[5];
    #pragma unroll
    for (int i = 0; i < 5; ++i) {
        pA[i] = *(const f16x4*)(gb + (size_t)0 * NCOL + 16 * i);
        pB[i] = *(const f16x4*)(gb + (size_t)1 * NCOL + 16 * i);
    }

    #pragma unroll 1
    for (int tb = 0; tb < TLEN; tb += 2) {
        lstm_step9(tb,     pA, gb, afrag, hbufs, cst, grp, sel, wr, wel);
        lstm_step9(tb + 1, pB, gb, afrag, hbufs, cst, grp, sel, wr, wel);
    }

    // Final projection (step 2047 wrote buffer 0; h is linear there).
    if (tid < 2) {
        float s = last_b[tid];
        for (int j = 0; j < 150; ++j)
            s += (float)hbufs[j] * last_w[tid * 150 + j];
        out[b * 2 + tid] = s;
    }
}

// ---------------------------------------------------------------------------
extern "C" void kernel_launch(void* const* d_in, const int* in_sizes, int n_in,
                              void* d_out, int out_size, void* d_ws, size_t ws_size,
                              hipStream_t stream) {
    const float* inp    = (const float*)d_in[0];
    const float* conv_w = (const float*)d_in[1];
    const float* conv_b = (const float*)d_in[2];
    const float* w_ih   = (const float*)d_in[3];
    const float* w_hh   = (const float*)d_in[4];
    const float* b_ih   = (const float*)d_in[5];
    const float* b_hh   = (const float*)d_in[6];
    const float* last_w = (const float*)d_in[7];
    const float* last_b = (const float*)d_in[8];
    float* out = (float*)d_out;

    char* ws = (char*)d_ws;
    f16*   y      = (f16*)(ws);                        // 32768*160*2   = 10,485,760 B
    f16*   gates3 = (f16*)(ws + 10485760);             // 16*2050*640*2 = 41,984,000 B
    f16*   wihf   = (f16*)(ws + 10485760 + 41984000);          // 204,800 B
    f16*   whhf   = (f16*)(ws + 10485760 + 41984000 + 204800); // 204,800 B
    float* biasp  = (float*)(ws + 10485760 + 41984000 + 409600); // 2,560 B

    prep_weights<<<120, 256, 0, stream>>>(w_ih, w_hh, b_ih, b_hh, wihf, whhf, biasp);
    conv_relu<<<8192, 256, 0, stream>>>(inp, conv_w, conv_b, y);
    gates_gemm<<<2048, 640, 0, stream>>>(y, wihf, biasp, gates3);
    lstm_scan<<<16, 512, 0, stream>>>(gates3, whhf, last_w, last_b, out);
}

// Round 8
// 1464.250 us; speedup vs baseline: 1.1485x; 1.0132x over previous
//
#include <hip/hip_runtime.h>

typedef _Float16 f16;
typedef _Float16 f16x4 __attribute__((ext_vector_type(4)));
typedef _Float16 f16x8 __attribute__((ext_vector_type(8)));
typedef float f32x4 __attribute__((ext_vector_type(4)));

#define TLEN 2048
#define TPAD 2050     // gates3 time extent (2 pad steps: prefetch needs no clamp)
#define NCOL 640      // padded columns: 160 units x 4 gates, col = u*4 + G
#define GSTEP (16 * NCOL)   // f16 elements per timestep in gates3 [t][b][col]
#define K1   1.4426950408889634f   // log2(e)
#define K2   2.8853900817779268f   // 2*log2(e)

__device__ __forceinline__ f16x8 as_f16x8(f32x4 v) {
    union { f32x4 f; f16x8 h; } u; u.f = v; return u.h;
}

// ---------------------------------------------------------------------------
// Prep: MFMA fragment-ordered fp16 w_ih / w_hh, columns ordered
// col = unit*4 + gate, PRE-SCALED per gate (i,f,o: -K1; g: +K2) so the
// scan's exp2 args need no multiply.  Fragment layout:
// [nt(40)][kt(5)][lane(64)][e(8)], col = nt*16 + (lane&15),
// k = kt*32 + (lane>>4)*8 + e.  biasp[col] gets the same scale.
// ---------------------------------------------------------------------------
__global__ void prep_weights(const float* __restrict__ w_ih,
                             const float* __restrict__ w_hh,
                             const float* __restrict__ b_ih,
                             const float* __restrict__ b_hh,
                             f16* __restrict__ wihf, f16* __restrict__ whhf,
                             float* __restrict__ biasp)
{
    const int idx = blockIdx.x * blockDim.x + threadIdx.x;
    const int stride = gridDim.x * blockDim.x;
    for (int i = idx; i < 40 * 5 * 64 * 8; i += stride) {
        const int e = i & 7;
        const int lane = (i >> 3) & 63;
        const int kt = (i >> 9) % 5;
        const int nt = i / 2560;
        const int colg = nt * 16 + (lane & 15);
        const int u = colg >> 2, G = colg & 3;
        const int k = kt * 32 + (lane >> 4) * 8 + e;
        const float sc = (G == 2) ? K2 : -K1;
        f16 vi = (f16)0.f, vh = (f16)0.f;
        if (u < 150) {
            const int row = G * 150 + u;
            if (k < 144) vi = (f16)(w_ih[row * 144 + k] * sc);
            if (k < 150) vh = (f16)(w_hh[row * 150 + k] * sc);
        }
        wihf[i] = vi;
        whhf[i] = vh;
    }
    for (int i = idx; i < NCOL; i += stride) {
        const int u = i >> 2, G = i & 3;
        const float sc = (G == 2) ? K2 : -K1;
        biasp[i] = (u < 150) ? (b_ih[G * 150 + u] + b_hh[G * 150 + u]) * sc : 0.f;
    }
}

// ---------------------------------------------------------------------------
// Conv 3x3 VALID (17->4) + bias + ReLU.  4 (b,t) tiles per 256-thread block.
// Writes y in [t*16+b][160] fp16 (K padded 144->160 with zeros).
// ---------------------------------------------------------------------------
__global__ __launch_bounds__(256) void conv_relu(
    const float* __restrict__ in, const float* __restrict__ cw,
    const float* __restrict__ cb, f16* __restrict__ y)
{
    __shared__ float s_in[4][1088];
    __shared__ float s_w[612];
    __shared__ float s_b[4];
    const int tid = threadIdx.x, sub = tid >> 6, lt = tid & 63;
    const int bt = blockIdx.x * 4 + sub;
    const float* ip = in + (size_t)bt * 1088;
    #pragma unroll
    for (int i = 0; i < 17; ++i) s_in[sub][lt + i * 64] = ip[lt + i * 64];
    for (int i = tid; i < 612; i += 256) s_w[i] = cw[i];
    if (tid < 4) s_b[tid] = cb[tid];
    __syncthreads();
    const int b = bt >> 11, t = bt & 2047;
    f16* yr = y + (size_t)(t * 16 + b) * 160;
    for (int i = lt; i < 160; i += 64) {
        float v = 0.f;
        if (i < 144) {
            const int oc = i / 36, rr = i % 36, oy = rr / 6, ox = rr % 6;
            float acc = s_b[oc];
            const float* wp = s_w + oc * 153;
            const float* bp = &s_in[sub][oy * 8 + ox];
            #pragma unroll
            for (int ic = 0; ic < 17; ++ic)
                #pragma unroll
                for (int ky = 0; ky < 3; ++ky)
                    #pragma unroll
                    for (int kx = 0; kx < 3; ++kx)
                        acc += bp[ic * 64 + ky * 8 + kx] * wp[ic * 9 + ky * 3 + kx];
            v = fmaxf(acc, 0.f);
        }
        yr[i] = (f16)v;
    }
}

// ---------------------------------------------------------------------------
// gates_x = y @ w_ih_scaled^T + bias_scaled.  One block (10 waves x 4 tiles)
// per timestep.  Output layout [t][b(16)][col(640)] flat f16: each block's
// stores cover one contiguous 20 KB row-group (coalesced), and the scan
// WG b streams rows (t*16+b) with full-cacheline reads.
// ---------------------------------------------------------------------------
__global__ __launch_bounds__(640, 1) void gates_gemm(
    const f16* __restrict__ y, const f16* __restrict__ wihf,
    const float* __restrict__ biasp, f16* __restrict__ gates3)
{
    const int tid = threadIdx.x, wv = tid >> 6, lane = tid & 63;
    const int col = lane & 15, grp = lane >> 4;
    const int t = blockIdx.x;
    f16x8 a[5];
    const f16* yr = y + (size_t)(t * 16 + col) * 160;
    #pragma unroll
    for (int kt = 0; kt < 5; ++kt)
        a[kt] = *(const f16x8*)(yr + kt * 32 + grp * 8);
    #pragma unroll
    for (int i = 0; i < 4; ++i) {
        const int nt = wv * 4 + i;
        f32x4 acc = {0.f, 0.f, 0.f, 0.f};
        const f16* wf = wihf + (size_t)(nt * 5) * 512;
        #pragma unroll
        for (int kt = 0; kt < 5; ++kt) {
            f16x8 bf = *(const f16x8*)(wf + kt * 512 + lane * 8);
            acc = __builtin_amdgcn_mfma_f32_16x16x32_f16(a[kt], bf, acc, 0, 0, 0);
        }
        const int colg = nt * 16 + col;
        const float bb = biasp[colg];
        #pragma unroll
        for (int r = 0; r < 4; ++r)
            gates3[((size_t)(t * 16 + grp * 4 + r)) * NCOL + colg] = (f16)(acc[r] + bb);
    }
}

// ---------------------------------------------------------------------------
// Batch-parallel persistent LSTM scan: 16 WGs (one batch row each), 512
// threads = 8 waves = 2/SIMD (balanced: 50 MFMA/SIMD/step = 970-cyc matrix
// pipe floor).  A = w_hh fragments (resident), B = h broadcast from a linear
// 160-f16 LDS double buffer (conflict-free).  Lane (col,grp) of tile i holds
// all 4 gates of unit 4(5w+i)+grp in its acc regs; cols 0-4 do the act for
// tile=col (one act chain per lane), no gather.
// TAIL SCHEDULING: the MFMA C-in IS the pre-converted gates_x register
// array gx (converted one step ago).  Post-barrier order: issue 5 B-reads ->
// (in the read shadow) convert next step's raw pf -> gx, issue t+2 pf
// loads -> MFMA -> act -> write -> lgkmcnt-only drain -> barrier.  Global
// prefetches stay in flight across barriers (vmcnt never drained).
// ---------------------------------------------------------------------------
__device__ __forceinline__ void lstm_stepX(
    int t,
    f32x4 (&gxc)[5],          // this step's gates_x (f32, consumed as acc)
    f16x4 (&pfc)[5],          // raw slot to REFILL with step t+2
    f16x4 (&pfo)[5],          // raw gates for step t+1 (convert now)
    f32x4 (&gxo)[5],          // f32 destination for step t+1
    const f16* __restrict__ gb,
    const f32x4 (&afrag)[5][5], f16* hbufs, float& cst,
    int grp, int sel, bool wr, int wel)
{
    const int cur = t & 1;

    // 1) Issue all B-fragment reads first (broadcast, conflict-free).
    const f16* hr = hbufs + cur * 160 + grp * 8;
    f16x8 bf[5];
    #pragma unroll
    for (int kt = 0; kt < 5; ++kt)
        bf[kt] = *(const f16x8*)(hr + kt * 32);

    // 2) Fill the read-latency shadow with next-step prep (barrier-indep):
    //    refill pfc with t+2; convert pfo (t+1 raw) -> gxo.
    #pragma unroll
    for (int i = 0; i < 5; ++i)
        pfc[i] = *(const f16x4*)(gb + (size_t)(t + 2) * GSTEP + 16 * i);
    #pragma unroll
    for (int i = 0; i < 5; ++i) {
        gxo[i][0] = (float)pfo[i][0];
        gxo[i][1] = (float)pfo[i][1];
        gxo[i][2] = (float)pfo[i][2];
        gxo[i][3] = (float)pfo[i][3];
    }

    // 3) MFMA: acc-in is gxc directly (no init instructions on this path).
    #pragma unroll
    for (int kt = 0; kt < 5; ++kt)
        #pragma unroll
        for (int i = 0; i < 5; ++i)
            gxc[i] = __builtin_amdgcn_mfma_f32_16x16x32_f16(
                afrag[i][kt], bf[kt], gxc[i], 0, 0, 0);

    // 4) Select this lane's tile (sel = col for col<5), activation, write.
    float g0 = gxc[0][0], g1 = gxc[0][1], g2 = gxc[0][2], g3 = gxc[0][3];
    #pragma unroll
    for (int i = 1; i < 5; ++i) {
        const bool p = (sel == i);
        g0 = p ? gxc[i][0] : g0;
        g1 = p ? gxc[i][1] : g1;
        g2 = p ? gxc[i][2] : g2;
        g3 = p ? gxc[i][3] : g3;
    }
    const float ei = __builtin_amdgcn_exp2f(fminf(g0, 38.f));   // e^{-i}
    const float ef = __builtin_amdgcn_exp2f(fminf(g1, 38.f));   // e^{-f}
    const float eg = __builtin_amdgcn_exp2f(fminf(g2, 38.f));   // e^{2g}
    const float eo = __builtin_amdgcn_exp2f(fminf(g3, 38.f));   // e^{-o}
    const float sig_i = __builtin_amdgcn_rcpf(1.f + ei);
    const float sig_f = __builtin_amdgcn_rcpf(1.f + ef);
    const float sig_o = __builtin_amdgcn_rcpf(1.f + eo);
    const float tng   = (eg - 1.f) * __builtin_amdgcn_rcpf(eg + 1.f);
    const float c = sig_f * cst + sig_i * tng;
    cst = c;
    const float ec = __builtin_amdgcn_exp2f(fminf(K2 * c, 80.f));
    const float tnc = (ec - 1.f) * __builtin_amdgcn_rcpf(ec + 1.f);
    if (wr) hbufs[(cur ^ 1) * 160 + wel] = (f16)(sig_o * tnc);

    // 5) Drain LDS ops only; ONE raw barrier per step.
    asm volatile("s_waitcnt lgkmcnt(0)" ::: "memory");
    __builtin_amdgcn_s_barrier();
    __builtin_amdgcn_sched_barrier(0);
}

__global__ __launch_bounds__(512, 1) void lstm_scan(
    const f16* __restrict__ gates3, const f16* __restrict__ whhf,
    const float* __restrict__ last_w, const float* __restrict__ last_b,
    float* __restrict__ out)
{
    __shared__ __align__(16) f16 hbufs[2 * 160];   // linear h, double-buffered
    const int b = blockIdx.x;
    const int tid = threadIdx.x, w = tid >> 6, lane = tid & 63;
    const int col = lane & 15, grp = lane >> 4;
    const int sel = (col < 5) ? col : ((col < 10) ? col - 5 : ((col < 15) ? col - 10 : 0));
    const bool wr = (col < 5);
    const int wel = 20 * w + 4 * sel + grp;        // h index this lane writes

    for (int i = tid; i < 2 * 160; i += 512) hbufs[i] = (f16)0.f;

    // w_hh A-fragments for this wave's 5 tiles (resident in VGPR/AGPR file).
    f32x4 afrag[5][5];
    #pragma unroll
    for (int i = 0; i < 5; ++i)
        #pragma unroll
        for (int kt = 0; kt < 5; ++kt)
            afrag[i][kt] =
                *(const f32x4*)(whhf + (size_t)((((5 * w + i) * 5) + kt) * 64 + lane) * 8);

    float cst = 0.f;
    __syncthreads();

    // Gates base ([t][b][col] layout): lane consumes cols 80w+16i+4grp+(0..3)
    // of row (t*16 + b).
    const f16* gb = gates3 + (size_t)b * NCOL + 80 * w + 4 * grp;

    f16x4 pA[5], pB[5];
    f32x4 gxA[5], gxB[5];
    #pragma unroll
    for (int i = 0; i < 5; ++i) {
        pA[i] = *(const f16x4*)(gb + (size_t)0 * GSTEP + 16 * i);
        pB[i] = *(const f16x4*)(gb + (size_t)1 * GSTEP + 16 * i);
    }
    #pragma unroll
    for (int i = 0; i < 5; ++i) {
        gxA[i][0] = (float)pA[i][0];
        gxA[i][1] = (float)pA[i][1];
        gxA[i][2] = (float)pA[i][2];
        gxA[i][3] = (float)pA[i][3];
    }

    #pragma unroll 1
    for (int tb = 0; tb < TLEN; tb += 2) {
        // step tb:   consume gxA; refill pA with tb+2; convert pB -> gxB
        lstm_stepX(tb,     gxA, pA, pB, gxB, gb, afrag, hbufs, cst, grp, sel, wr, wel);
        // step tb+1: consume gxB; refill pB with tb+3; convert pA -> gxA
        lstm_stepX(tb + 1, gxB, pB, pA, gxA, gb, afrag, hbufs, cst, grp, sel, wr, wel);
    }

    // Final projection (step 2047 wrote buffer 0; h is linear there).
    if (tid < 2) {
        float s = last_b[tid];
        for (int j = 0; j < 150; ++j)
            s += (float)hbufs[j] * last_w[tid * 150 + j];
        out[b * 2 + tid] = s;
    }
}

// ---------------------------------------------------------------------------
extern "C" void kernel_launch(void* const* d_in, const int* in_sizes, int n_in,
                              void* d_out, int out_size, void* d_ws, size_t ws_size,
                              hipStream_t stream) {
    const float* inp    = (const float*)d_in[0];
    const float* conv_w = (const float*)d_in[1];
    const float* conv_b = (const float*)d_in[2];
    const float* w_ih   = (const float*)d_in[3];
    const float* w_hh   = (const float*)d_in[4];
    const float* b_ih   = (const float*)d_in[5];
    const float* b_hh   = (const float*)d_in[6];
    const float* last_w = (const float*)d_in[7];
    const float* last_b = (const float*)d_in[8];
    float* out = (float*)d_out;

    char* ws = (char*)d_ws;
    f16*   y      = (f16*)(ws);                        // 32768*160*2   = 10,485,760 B
    f16*   gates3 = (f16*)(ws + 10485760);             // 2050*16*640*2 = 41,984,000 B
    f16*   wihf   = (f16*)(ws + 10485760 + 41984000);          // 204,800 B
    f16*   whhf   = (f16*)(ws + 10485760 + 41984000 + 204800); // 204,800 B
    float* biasp  = (float*)(ws + 10485760 + 41984000 + 409600); // 2,560 B

    prep_weights<<<120, 256, 0, stream>>>(w_ih, w_hh, b_ih, b_hh, wihf, whhf, biasp);
    conv_relu<<<8192, 256, 0, stream>>>(inp, conv_w, conv_b, y);
    gates_gemm<<<2048, 640, 0, stream>>>(y, wihf, biasp, gates3);
    lstm_scan<<<16, 512, 0, stream>>>(gates3, whhf, last_w, last_b, out);
}

// Round 9
// 1399.663 us; speedup vs baseline: 1.2015x; 1.0461x over previous
//
#include <hip/hip_runtime.h>

typedef _Float16 f16;
typedef _Float16 f16x4 __attribute__((ext_vector_type(4)));
typedef _Float16 f16x8 __attribute__((ext_vector_type(8)));
typedef float f32x4 __attribute__((ext_vector_type(4)));

#define TLEN 2048
#define TPAD 2050     // gates3 time extent (2 pad steps: prefetch needs no clamp)
#define NCOL 640      // padded columns: 160 units x 4 gates, col = u*4 + G
#define GSTEP (16 * NCOL)   // f16 elements per timestep in gates3 [t][b][col]
#define K1   1.4426950408889634f   // log2(e)
#define K2   2.8853900817779268f   // 2*log2(e)

__device__ __forceinline__ f16x8 as_f16x8(f32x4 v) {
    union { f32x4 f; f16x8 h; } u; u.f = v; return u.h;
}

// ---------------------------------------------------------------------------
// Prep: MFMA fragment-ordered fp16 w_ih / w_hh, columns ordered
// col = unit*4 + gate, PRE-SCALED per gate (i,f,o: -K1; g: +K2) so the
// scan's exp2 args need no multiply.  Fragment layout:
// [nt(40)][kt(5)][lane(64)][e(8)], col = nt*16 + (lane&15),
// k = kt*32 + (lane>>4)*8 + e.  biasp[col] gets the same scale.
// ---------------------------------------------------------------------------
__global__ void prep_weights(const float* __restrict__ w_ih,
                             const float* __restrict__ w_hh,
                             const float* __restrict__ b_ih,
                             const float* __restrict__ b_hh,
                             f16* __restrict__ wihf, f16* __restrict__ whhf,
                             float* __restrict__ biasp)
{
    const int idx = blockIdx.x * blockDim.x + threadIdx.x;
    const int stride = gridDim.x * blockDim.x;
    for (int i = idx; i < 40 * 5 * 64 * 8; i += stride) {
        const int e = i & 7;
        const int lane = (i >> 3) & 63;
        const int kt = (i >> 9) % 5;
        const int nt = i / 2560;
        const int colg = nt * 16 + (lane & 15);
        const int u = colg >> 2, G = colg & 3;
        const int k = kt * 32 + (lane >> 4) * 8 + e;
        const float sc = (G == 2) ? K2 : -K1;
        f16 vi = (f16)0.f, vh = (f16)0.f;
        if (u < 150) {
            const int row = G * 150 + u;
            if (k < 144) vi = (f16)(w_ih[row * 144 + k] * sc);
            if (k < 150) vh = (f16)(w_hh[row * 150 + k] * sc);
        }
        wihf[i] = vi;
        whhf[i] = vh;
    }
    for (int i = idx; i < NCOL; i += stride) {
        const int u = i >> 2, G = i & 3;
        const float sc = (G == 2) ? K2 : -K1;
        biasp[i] = (u < 150) ? (b_ih[G * 150 + u] + b_hh[G * 150 + u]) * sc : 0.f;
    }
}

// ---------------------------------------------------------------------------
// Conv 3x3 VALID (17->4) + bias + ReLU.  4 (b,t) tiles per 256-thread block.
// Writes y in [t*16+b][160] fp16 (K padded 144->160 with zeros).
// ---------------------------------------------------------------------------
__global__ __launch_bounds__(256) void conv_relu(
    const float* __restrict__ in, const float* __restrict__ cw,
    const float* __restrict__ cb, f16* __restrict__ y)
{
    __shared__ float s_in[4][1088];
    __shared__ float s_w[612];
    __shared__ float s_b[4];
    const int tid = threadIdx.x, sub = tid >> 6, lt = tid & 63;
    const int bt = blockIdx.x * 4 + sub;
    const float* ip = in + (size_t)bt * 1088;
    #pragma unroll
    for (int i = 0; i < 17; ++i) s_in[sub][lt + i * 64] = ip[lt + i * 64];
    for (int i = tid; i < 612; i += 256) s_w[i] = cw[i];
    if (tid < 4) s_b[tid] = cb[tid];
    __syncthreads();
    const int b = bt >> 11, t = bt & 2047;
    f16* yr = y + (size_t)(t * 16 + b) * 160;
    for (int i = lt; i < 160; i += 64) {
        float v = 0.f;
        if (i < 144) {
            const int oc = i / 36, rr = i % 36, oy = rr / 6, ox = rr % 6;
            float acc = s_b[oc];
            const float* wp = s_w + oc * 153;
            const float* bp = &s_in[sub][oy * 8 + ox];
            #pragma unroll
            for (int ic = 0; ic < 17; ++ic)
                #pragma unroll
                for (int ky = 0; ky < 3; ++ky)
                    #pragma unroll
                    for (int kx = 0; kx < 3; ++kx)
                        acc += bp[ic * 64 + ky * 8 + kx] * wp[ic * 9 + ky * 3 + kx];
            v = fmaxf(acc, 0.f);
        }
        yr[i] = (f16)v;
    }
}

// ---------------------------------------------------------------------------
// gates_x = y @ w_ih_scaled^T + bias_scaled.  One block (10 waves x 4 tiles)
// per timestep.  Output layout [t][b(16)][col(640)] flat f16.
// ---------------------------------------------------------------------------
__global__ __launch_bounds__(640, 1) void gates_gemm(
    const f16* __restrict__ y, const f16* __restrict__ wihf,
    const float* __restrict__ biasp, f16* __restrict__ gates3)
{
    const int tid = threadIdx.x, wv = tid >> 6, lane = tid & 63;
    const int col = lane & 15, grp = lane >> 4;
    const int t = blockIdx.x;
    f16x8 a[5];
    const f16* yr = y + (size_t)(t * 16 + col) * 160;
    #pragma unroll
    for (int kt = 0; kt < 5; ++kt)
        a[kt] = *(const f16x8*)(yr + kt * 32 + grp * 8);
    #pragma unroll
    for (int i = 0; i < 4; ++i) {
        const int nt = wv * 4 + i;
        f32x4 acc = {0.f, 0.f, 0.f, 0.f};
        const f16* wf = wihf + (size_t)(nt * 5) * 512;
        #pragma unroll
        for (int kt = 0; kt < 5; ++kt) {
            f16x8 bf = *(const f16x8*)(wf + kt * 512 + lane * 8);
            acc = __builtin_amdgcn_mfma_f32_16x16x32_f16(a[kt], bf, acc, 0, 0, 0);
        }
        const int colg = nt * 16 + col;
        const float bb = biasp[colg];
        #pragma unroll
        for (int r = 0; r < 4; ++r)
            gates3[((size_t)(t * 16 + grp * 4 + r)) * NCOL + colg] = (f16)(acc[r] + bb);
    }
}

// ---------------------------------------------------------------------------
// Batch-parallel persistent LSTM scan: 16 WGs (one batch row each), 512
// threads = 8 waves = 2/SIMD (balanced: 50 MFMA/SIMD/step).  A = w_hh
// fragments (resident), B = h broadcast from a linear 160-f16 LDS double
// buffer (conflict-free).
// KEY FIX vs r8: only the SELECTED tile's gates_x is ever consumed (the
// post-MFMA select discards the other 4 tiles' accumulators), so each lane
// loads exactly ONE f16x4 -- its own unit's 4 gate-x values -- and the
// converted gxf is the shared C-init for ALL five tiles' kt=0 MFMA
// (garbage+gxf in unselected tiles is discarded).  Per wave per step:
// loads 5->1, cvt 20->4, one pointer advanced by GSTEP.
// ---------------------------------------------------------------------------
__device__ __forceinline__ void lstm_stepY(
    int t, f16x4& pfu, f16x4& pfc, const f16*& pLoad,
    const f32x4 (&afrag)[5][5], f16* hbufs, float& cst,
    int grp, int sel, bool wr, int wel)
{
    const int cur = t & 1;

    // 1) Issue B-fragment reads (broadcast, conflict-free).
    const f16* hr = hbufs + cur * 160 + grp * 8;
    f16x8 bf[5];
    #pragma unroll
    for (int kt = 0; kt < 5; ++kt)
        bf[kt] = *(const f16x8*)(hr + kt * 32);

    // 2) In the read shadow: convert this step's unit-gates (loaded 2 steps
    //    ago) and refill the slot with step t+2 (stays in flight across
    //    barriers; vmcnt never drained).
    f32x4 gxf;
    gxf[0] = (float)pfu[0];
    gxf[1] = (float)pfu[1];
    gxf[2] = (float)pfu[2];
    gxf[3] = (float)pfu[3];
    pfc = *(const f16x4*)pLoad;
    pLoad += GSTEP;

    // 3) MFMA: kt=0 uses gxf as C-in for ALL tiles (only the selected
    //    tile's result is consumed); kt=1..4 chain.
    f32x4 acc[5];
    #pragma unroll
    for (int i = 0; i < 5; ++i)
        acc[i] = __builtin_amdgcn_mfma_f32_16x16x32_f16(
            afrag[i][0], bf[0], gxf, 0, 0, 0);
    #pragma unroll
    for (int kt = 1; kt < 5; ++kt)
        #pragma unroll
        for (int i = 0; i < 5; ++i)
            acc[i] = __builtin_amdgcn_mfma_f32_16x16x32_f16(
                afrag[i][kt], bf[kt], acc[i], 0, 0, 0);

    // 4) Select this lane's tile (sel = col mod 5; masks loop-invariant).
    float g0 = acc[0][0], g1 = acc[0][1], g2 = acc[0][2], g3 = acc[0][3];
    #pragma unroll
    for (int i = 1; i < 5; ++i) {
        const bool p = (sel == i);
        g0 = p ? acc[i][0] : g0;
        g1 = p ? acc[i][1] : g1;
        g2 = p ? acc[i][2] : g2;
        g3 = p ? acc[i][3] : g3;
    }

    // 5) Activation (pre-scaled args; direct form, short critical path).
    const float ei = __builtin_amdgcn_exp2f(fminf(g0, 38.f));   // e^{-i}
    const float ef = __builtin_amdgcn_exp2f(fminf(g1, 38.f));   // e^{-f}
    const float eg = __builtin_amdgcn_exp2f(fminf(g2, 38.f));   // e^{2g}
    const float eo = __builtin_amdgcn_exp2f(fminf(g3, 38.f));   // e^{-o}
    const float sig_i = __builtin_amdgcn_rcpf(1.f + ei);
    const float sig_f = __builtin_amdgcn_rcpf(1.f + ef);
    const float sig_o = __builtin_amdgcn_rcpf(1.f + eo);
    const float tng   = (eg - 1.f) * __builtin_amdgcn_rcpf(eg + 1.f);
    const float c = sig_f * cst + sig_i * tng;
    cst = c;
    const float ec = __builtin_amdgcn_exp2f(fminf(K2 * c, 80.f));
    const float tnc = (ec - 1.f) * __builtin_amdgcn_rcpf(ec + 1.f);
    if (wr) hbufs[(cur ^ 1) * 160 + wel] = (f16)(sig_o * tnc);

    // 6) Drain LDS ops only; ONE raw barrier per step.
    asm volatile("s_waitcnt lgkmcnt(0)" ::: "memory");
    __builtin_amdgcn_s_barrier();
    __builtin_amdgcn_sched_barrier(0);
}

__global__ __launch_bounds__(512, 1) void lstm_scan(
    const f16* __restrict__ gates3, const f16* __restrict__ whhf,
    const float* __restrict__ last_w, const float* __restrict__ last_b,
    float* __restrict__ out)
{
    __shared__ __align__(16) f16 hbufs[2 * 160];   // linear h, double-buffered
    const int b = blockIdx.x;
    const int tid = threadIdx.x, w = tid >> 6, lane = tid & 63;
    const int col = lane & 15, grp = lane >> 4;
    const int sel = (col < 5) ? col : ((col < 10) ? col - 5 : ((col < 15) ? col - 10 : 0));
    const bool wr = (col < 5);
    const int wel = 20 * w + 4 * sel + grp;        // h index this lane writes

    for (int i = tid; i < 2 * 160; i += 512) hbufs[i] = (f16)0.f;

    // w_hh A-fragments for this wave's 5 tiles (resident in VGPR/AGPR file).
    f32x4 afrag[5][5];
    #pragma unroll
    for (int i = 0; i < 5; ++i)
        #pragma unroll
        for (int kt = 0; kt < 5; ++kt)
            afrag[i][kt] =
                *(const f32x4*)(whhf + (size_t)((((5 * w + i) * 5) + kt) * 64 + lane) * 8);

    float cst = 0.f;
    __syncthreads();

    // This lane's unit-gates column: col 80w + 16sel + 4grp (+G in 0..3).
    const f16* gbu = gates3 + (size_t)b * NCOL + 80 * w + 16 * sel + 4 * grp;

    f16x4 pA = *(const f16x4*)(gbu);
    f16x4 pB = *(const f16x4*)(gbu + (size_t)1 * GSTEP);
    const f16* pLoad = gbu + (size_t)2 * GSTEP;    // next to fetch: t = 2

    #pragma unroll 1
    for (int tb = 0; tb < TLEN; tb += 2) {
        lstm_stepY(tb,     pA, pA, pLoad, afrag, hbufs, cst, grp, sel, wr, wel);
        lstm_stepY(tb + 1, pB, pB, pLoad, afrag, hbufs, cst, grp, sel, wr, wel);
    }

    // Final projection (step 2047 wrote buffer 0; h is linear there).
    if (tid < 2) {
        float s = last_b[tid];
        for (int j = 0; j < 150; ++j)
            s += (float)hbufs[j] * last_w[tid * 150 + j];
        out[b * 2 + tid] = s;
    }
}

// ---------------------------------------------------------------------------
extern "C" void kernel_launch(void* const* d_in, const int* in_sizes, int n_in,
                              void* d_out, int out_size, void* d_ws, size_t ws_size,
                              hipStream_t stream) {
    const float* inp    = (const float*)d_in[0];
    const float* conv_w = (const float*)d_in[1];
    const float* conv_b = (const float*)d_in[2];
    const float* w_ih   = (const float*)d_in[3];
    const float* w_hh   = (const float*)d_in[4];
    const float* b_ih   = (const float*)d_in[5];
    const float* b_hh   = (const float*)d_in[6];
    const float* last_w = (const float*)d_in[7];
    const float* last_b = (const float*)d_in[8];
    float* out = (float*)d_out;

    char* ws = (char*)d_ws;
    f16*   y      = (f16*)(ws);                        // 32768*160*2   = 10,485,760 B
    f16*   gates3 = (f16*)(ws + 10485760);             // 2050*16*640*2 = 41,984,000 B
    f16*   wihf   = (f16*)(ws + 10485760 + 41984000);          // 204,800 B
    f16*   whhf   = (f16*)(ws + 10485760 + 41984000 + 204800); // 204,800 B
    float* biasp  = (float*)(ws + 10485760 + 41984000 + 409600); // 2,560 B

    prep_weights<<<120, 256, 0, stream>>>(w_ih, w_hh, b_ih, b_hh, wihf, whhf, biasp);
    conv_relu<<<8192, 256, 0, stream>>>(inp, conv_w, conv_b, y);
    gates_gemm<<<2048, 640, 0, stream>>>(y, wihf, biasp, gates3);
    lstm_scan<<<16, 512, 0, stream>>>(gates3, whhf, last_w, last_b, out);
}